// Round 10
// baseline (718.742 us; speedup 1.0000x reference)
//
#include <hip/hip_runtime.h>

#define BN_EPS 1e-5f

// Bucket-sort parameters: NPB nodes per bucket (pow2), PB placement blocks.
#define NPB 512
#define NPB_SHIFT 9
#define PB 512
#define MAXB 256
// BN-stat accumulator slices (atomic-depth reduction)
#define NSLICE 16

typedef __attribute__((ext_vector_type(8))) short short8;
typedef __attribute__((ext_vector_type(4))) float floatx4;

__device__ __forceinline__ unsigned short f2bf(float f) {
    unsigned u = __float_as_uint(f);
    unsigned r = u + 0x7FFFu + ((u >> 16) & 1u);   // round-to-nearest-even
    return (unsigned short)(r >> 16);
}
__device__ __forceinline__ float blo(unsigned v) { return __uint_as_float(v << 16); }
__device__ __forceinline__ float bhi(unsigned v) { return __uint_as_float(v & 0xffff0000u); }

// ---------------- W pre-transpose: wt[n][k] = bf16(W[k][n]) ----------------
__global__ __launch_bounds__(256) void wconv(
    const float* __restrict__ W0, const float* __restrict__ W1,
    unsigned short* __restrict__ wt0, unsigned short* __restrict__ wt1)
{
    const int idx = blockIdx.x * 256 + threadIdx.x;   // < 16384
    const int n = idx >> 7, k = idx & 127;
    wt0[idx] = f2bf(W0[k * 128 + n]);
    wt1[idx] = f2bf(W1[k * 128 + n]);
}

// ---------------- layer-0 GEMM: C[M x 128] = A_fp32 @ W ----------------
__global__ __launch_bounds__(256) void gemm0(
    const float* __restrict__ A, const unsigned short* __restrict__ Wt,
    unsigned short* __restrict__ C, int M)
{
    __shared__ char lds[53248];
    unsigned short* Al = (unsigned short*)lds;            // [64][136] bf16
    unsigned short* Wl = (unsigned short*)(lds + 17408);  // [128][136] bf16
    float* Cl = (float*)lds;                              // [64][132] f32 (reuse)

    const int tid = threadIdx.x;
    const int r0 = blockIdx.x * 64;

#pragma unroll
    for (int i = 0; i < 16; ++i) {
        const int idx = i * 256 + tid;          // ushort4 units
        const int n = idx >> 5, q = idx & 31;
        const ushort4 v = ((const ushort4*)Wt)[idx];
        *(ushort4*)&Wl[n * 136 + q * 4] = v;
    }
#pragma unroll
    for (int i = 0; i < 8; ++i) {
        const int row = i * 8 + (tid >> 5), q = tid & 31;
        const int gr = r0 + row;
        float4 v = (gr < M) ? ((const float4*)A)[(size_t)gr * 32 + q]
                            : make_float4(0.f, 0.f, 0.f, 0.f);
        ushort4 o;
        o.x = f2bf(v.x); o.y = f2bf(v.y); o.z = f2bf(v.z); o.w = f2bf(v.w);
        *(ushort4*)&Al[row * 136 + q * 4] = o;
    }
    __syncthreads();

    const int wave = tid >> 6, lane = tid & 63;
    const int lrow = lane & 15, quad = lane >> 4;
    const int n0 = wave * 32;

    floatx4 acc[4][2];
#pragma unroll
    for (int mt = 0; mt < 4; ++mt)
#pragma unroll
        for (int t = 0; t < 2; ++t)
#pragma unroll
            for (int j = 0; j < 4; ++j) acc[mt][t][j] = 0.f;

#pragma unroll
    for (int c = 0; c < 4; ++c) {
        const int k0 = c * 32;
        const short8 b0 = *(const short8*)&Wl[(n0 + lrow) * 136 + k0 + quad * 8];
        const short8 b1 = *(const short8*)&Wl[(n0 + 16 + lrow) * 136 + k0 + quad * 8];
#pragma unroll
        for (int mt = 0; mt < 4; ++mt) {
            const short8 a = *(const short8*)&Al[(mt * 16 + lrow) * 136 + k0 + quad * 8];
            acc[mt][0] = __builtin_amdgcn_mfma_f32_16x16x32_bf16(a, b0, acc[mt][0], 0, 0, 0);
            acc[mt][1] = __builtin_amdgcn_mfma_f32_16x16x32_bf16(a, b1, acc[mt][1], 0, 0, 0);
        }
    }
    __syncthreads();

#pragma unroll
    for (int mt = 0; mt < 4; ++mt)
#pragma unroll
        for (int t = 0; t < 2; ++t)
#pragma unroll
            for (int j = 0; j < 4; ++j)
                Cl[(mt * 16 + quad * 4 + j) * 132 + n0 + t * 16 + lrow] = acc[mt][t][j];
    __syncthreads();

#pragma unroll
    for (int i = 0; i < 4; ++i) {
        const int row = i * 16 + (tid >> 4);
        const int c0 = (tid & 15) * 8;
        const int gr = r0 + row;
        if (gr < M) {
            const float4 v0 = *(float4*)&Cl[row * 132 + c0];
            const float4 v1 = *(float4*)&Cl[row * 132 + c0 + 4];
            uint4 o;
            o.x = (unsigned)f2bf(v0.x) | ((unsigned)f2bf(v0.y) << 16);
            o.y = (unsigned)f2bf(v0.z) | ((unsigned)f2bf(v0.w) << 16);
            o.z = (unsigned)f2bf(v1.x) | ((unsigned)f2bf(v1.y) << 16);
            o.w = (unsigned)f2bf(v1.z) | ((unsigned)f2bf(v1.w) << 16);
            ((uint4*)C)[(size_t)gr * 16 + (c0 >> 3)] = o;
        }
    }
}

// ---------------- layer-1 GEMM: C = relu(BN(A_bf16)) @ W ----------------
// BN affine from SLICED raw stats (sum over NSLICE in prologue).
__global__ __launch_bounds__(256) void gemm1(
    const unsigned* __restrict__ Ab, const unsigned short* __restrict__ Wt,
    unsigned short* __restrict__ C,
    const float* __restrict__ sum, const float* __restrict__ sq,
    const float* __restrict__ g, const float* __restrict__ be,
    int M, int N)
{
    __shared__ char lds[53248];
    unsigned short* Al = (unsigned short*)lds;            // [64][136]
    unsigned short* Wl = (unsigned short*)(lds + 17408);  // [128][136]
    float* AscL = (float*)(lds + 52224);                  // [128]
    float* AshL = AscL + 128;
    float* Cl = (float*)lds;

    const int tid = threadIdx.x;
    const int r0 = blockIdx.x * 64;

    if (tid < 128) {
        float s = 0.f, q = 0.f;
#pragma unroll
        for (int k = 0; k < NSLICE; ++k) {
            s += sum[k * 128 + tid];
            q += sq[k * 128 + tid];
        }
        const float invN = 1.0f / (float)N;
        const float m = s * invN;
        const float var = q * invN - m * m;
        const float rs = rsqrtf(var + BN_EPS);
        AscL[tid] = g[tid] * rs;
        AshL[tid] = be[tid] - g[tid] * m * rs;
    }
    __syncthreads();

#pragma unroll
    for (int i = 0; i < 16; ++i) {
        const int idx = i * 256 + tid;
        const int n = idx >> 5, q = idx & 31;
        const ushort4 v = ((const ushort4*)Wt)[idx];
        *(ushort4*)&Wl[n * 136 + q * 4] = v;
    }
#pragma unroll
    for (int i = 0; i < 4; ++i) {
        const int idx = i * 256 + tid;
        const int row = idx >> 4, qc = idx & 15;
        const int gr = r0 + row;
        uint4 v = (gr < M) ? ((const uint4*)Ab)[(size_t)gr * 16 + qc]
                           : make_uint4(0, 0, 0, 0);
        const float4 a0 = *(const float4*)&AscL[qc * 8];
        const float4 a1 = *(const float4*)&AscL[qc * 8 + 4];
        const float4 b0 = *(const float4*)&AshL[qc * 8];
        const float4 b1 = *(const float4*)&AshL[qc * 8 + 4];
        float x0 = fmaxf(fmaf(a0.x, blo(v.x), b0.x), 0.f);
        float x1 = fmaxf(fmaf(a0.y, bhi(v.x), b0.y), 0.f);
        float x2 = fmaxf(fmaf(a0.z, blo(v.y), b0.z), 0.f);
        float x3 = fmaxf(fmaf(a0.w, bhi(v.y), b0.w), 0.f);
        float x4 = fmaxf(fmaf(a1.x, blo(v.z), b1.x), 0.f);
        float x5 = fmaxf(fmaf(a1.y, bhi(v.z), b1.y), 0.f);
        float x6 = fmaxf(fmaf(a1.z, blo(v.w), b1.z), 0.f);
        float x7 = fmaxf(fmaf(a1.w, bhi(v.w), b1.w), 0.f);
        uint4 o;
        o.x = (unsigned)f2bf(x0) | ((unsigned)f2bf(x1) << 16);
        o.y = (unsigned)f2bf(x2) | ((unsigned)f2bf(x3) << 16);
        o.z = (unsigned)f2bf(x4) | ((unsigned)f2bf(x5) << 16);
        o.w = (unsigned)f2bf(x6) | ((unsigned)f2bf(x7) << 16);
        *(uint4*)&Al[row * 136 + qc * 8] = o;
    }
    __syncthreads();

    const int wave = tid >> 6, lane = tid & 63;
    const int lrow = lane & 15, quad = lane >> 4;
    const int n0 = wave * 32;

    floatx4 acc[4][2];
#pragma unroll
    for (int mt = 0; mt < 4; ++mt)
#pragma unroll
        for (int t = 0; t < 2; ++t)
#pragma unroll
            for (int j = 0; j < 4; ++j) acc[mt][t][j] = 0.f;

#pragma unroll
    for (int c = 0; c < 4; ++c) {
        const int k0 = c * 32;
        const short8 b0 = *(const short8*)&Wl[(n0 + lrow) * 136 + k0 + quad * 8];
        const short8 b1 = *(const short8*)&Wl[(n0 + 16 + lrow) * 136 + k0 + quad * 8];
#pragma unroll
        for (int mt = 0; mt < 4; ++mt) {
            const short8 a = *(const short8*)&Al[(mt * 16 + lrow) * 136 + k0 + quad * 8];
            acc[mt][0] = __builtin_amdgcn_mfma_f32_16x16x32_bf16(a, b0, acc[mt][0], 0, 0, 0);
            acc[mt][1] = __builtin_amdgcn_mfma_f32_16x16x32_bf16(a, b1, acc[mt][1], 0, 0, 0);
        }
    }
    __syncthreads();

#pragma unroll
    for (int mt = 0; mt < 4; ++mt)
#pragma unroll
        for (int t = 0; t < 2; ++t)
#pragma unroll
            for (int j = 0; j < 4; ++j)
                Cl[(mt * 16 + quad * 4 + j) * 132 + n0 + t * 16 + lrow] = acc[mt][t][j];
    __syncthreads();

#pragma unroll
    for (int i = 0; i < 4; ++i) {
        const int row = i * 16 + (tid >> 4);
        const int c0 = (tid & 15) * 8;
        const int gr = r0 + row;
        if (gr < M) {
            const float4 v0 = *(float4*)&Cl[row * 132 + c0];
            const float4 v1 = *(float4*)&Cl[row * 132 + c0 + 4];
            uint4 o;
            o.x = (unsigned)f2bf(v0.x) | ((unsigned)f2bf(v0.y) << 16);
            o.y = (unsigned)f2bf(v0.z) | ((unsigned)f2bf(v0.w) << 16);
            o.z = (unsigned)f2bf(v1.x) | ((unsigned)f2bf(v1.y) << 16);
            o.w = (unsigned)f2bf(v1.z) | ((unsigned)f2bf(v1.w) << 16);
            ((uint4*)C)[(size_t)gr * 16 + (c0 >> 3)] = o;
        }
    }
}

// ============ atomic-free CSR build: two-level bucket counting sort ============

__global__ __launch_bounds__(256) void bucket_hist(
    const int* __restrict__ src, const int* __restrict__ dst,
    int* __restrict__ cntD, int* __restrict__ cntS, int E, int B, int chunk)
{
    __shared__ int hD[MAXB], hS[MAXB];
    const int tid = threadIdx.x;
    for (int i = tid; i < B; i += 256) { hD[i] = 0; hS[i] = 0; }
    __syncthreads();
    const int lo = blockIdx.x * chunk;
    const int hi = min(E, lo + chunk);
    for (int e = lo + tid; e < hi; e += 256) {
        atomicAdd(&hD[dst[e] >> NPB_SHIFT], 1);
        atomicAdd(&hS[src[e] >> NPB_SHIFT], 1);
    }
    __syncthreads();
    for (int i = tid; i < B; i += 256) {
        cntD[i * PB + blockIdx.x] = hD[i];
        cntS[i * PB + blockIdx.x] = hS[i];
    }
}

__global__ __launch_bounds__(256) void bucket_base(
    const int* __restrict__ cntD, const int* __restrict__ cntS,
    int* __restrict__ baseD, int* __restrict__ baseS, int B, int E)
{
    __shared__ int lD[256], lS[256];
    const int tid = threadIdx.x;
    int sD = 0, sS = 0;
    if (tid < B) {
        const int4* pD = (const int4*)(cntD + tid * PB);
        const int4* pS = (const int4*)(cntS + tid * PB);
        for (int j = 0; j < PB / 4; ++j) {
            const int4 a = pD[j], b = pS[j];
            sD += a.x + a.y + a.z + a.w;
            sS += b.x + b.y + b.z + b.w;
        }
    }
    lD[tid] = sD; lS[tid] = sS;
    __syncthreads();
    for (int st = 1; st < 256; st <<= 1) {
        const int vD = (tid >= st) ? lD[tid - st] : 0;
        const int vS = (tid >= st) ? lS[tid - st] : 0;
        __syncthreads();
        lD[tid] += vD; lS[tid] += vS;
        __syncthreads();
    }
    if (tid < B) { baseD[tid] = lD[tid] - sD; baseS[tid] = lS[tid] - sS; }
    if (tid == 0) { baseD[B] = E; baseS[B] = E; }
}

__global__ __launch_bounds__(256) void bucket_cursor(
    int* __restrict__ cntD, int* __restrict__ cntS,
    const int* __restrict__ baseD, const int* __restrict__ baseS, int B)
{
    int b = blockIdx.x;
    int* cnt; const int* base;
    if (b < B) { cnt = cntD; base = baseD; }
    else       { cnt = cntS; base = baseS; b -= B; }
    __shared__ int ls[256];
    const int tid = threadIdx.x;
    const int c0 = cnt[b * PB + 2 * tid];
    const int c1 = cnt[b * PB + 2 * tid + 1];
    const int s = c0 + c1;
    ls[tid] = s;
    __syncthreads();
    for (int st = 1; st < 256; st <<= 1) {
        const int v = (tid >= st) ? ls[tid - st] : 0;
        __syncthreads();
        ls[tid] += v;
        __syncthreads();
    }
    const int excl = ls[tid] - s + base[b];
    cnt[b * PB + 2 * tid] = excl;
    cnt[b * PB + 2 * tid + 1] = excl + c0;
}

__global__ __launch_bounds__(256) void bucket_place(
    const int* __restrict__ src, const int* __restrict__ dst,
    const float* __restrict__ ew,
    const int* __restrict__ curD, const int* __restrict__ curS,
    uint2* __restrict__ bktD, uint2* __restrict__ bktS, int E, int B, int chunk)
{
    __shared__ int cD[MAXB], cS[MAXB];
    const int tid = threadIdx.x;
    for (int i = tid; i < B; i += 256) {
        cD[i] = curD[i * PB + blockIdx.x];
        cS[i] = curS[i * PB + blockIdx.x];
    }
    __syncthreads();
    const int lo = blockIdx.x * chunk;
    const int hi = min(E, lo + chunk);
    for (int e = lo + tid; e < hi; e += 256) {
        const int s = src[e], d = dst[e];
        const unsigned wb = __float_as_uint(ew[e]);
        const int pd = atomicAdd(&cD[d >> NPB_SHIFT], 1);
        bktD[pd] = make_uint2(((unsigned)s << NPB_SHIFT) | (unsigned)(d & (NPB - 1)), wb);
        const int ps = atomicAdd(&cS[s >> NPB_SHIFT], 1);
        bktS[ps] = make_uint2((unsigned)(s & (NPB - 1)), wb);
    }
}

__global__ __launch_bounds__(256) void bucket_sort(
    const uint2* __restrict__ bktD, const int* __restrict__ baseD,
    int* __restrict__ rp, int2* __restrict__ packed, int N)
{
    const int b = blockIdx.x;
    const int lo = baseD[b], hi = baseD[b + 1];
    __shared__ int cnt[NPB], cur[NPB];
    __shared__ int ls[256];
    const int tid = threadIdx.x;
    cnt[2 * tid] = 0; cnt[2 * tid + 1] = 0;
    __syncthreads();
    for (int i = lo + tid; i < hi; i += 256)
        atomicAdd(&cnt[bktD[i].x & (NPB - 1)], 1);
    __syncthreads();
    const int c0 = cnt[2 * tid], c1 = cnt[2 * tid + 1];
    const int s = c0 + c1;
    ls[tid] = s;
    __syncthreads();
    for (int st = 1; st < 256; st <<= 1) {
        const int v = (tid >= st) ? ls[tid - st] : 0;
        __syncthreads();
        ls[tid] += v;
        __syncthreads();
    }
    const int excl = ls[tid] - s;
    const int n0 = b * NPB + 2 * tid;
    if (n0 < N)     rp[n0]     = lo + excl + c0;
    if (n0 + 1 < N) rp[n0 + 1] = lo + excl + c0 + c1;
    cur[2 * tid]     = lo + excl;
    cur[2 * tid + 1] = lo + excl + c0;
    __syncthreads();
    for (int i = lo + tid; i < hi; i += 256) {
        const uint2 r = bktD[i];
        const int pos = atomicAdd(&cur[r.x & (NPB - 1)], 1);
        packed[pos] = make_int2((int)(r.x >> NPB_SHIFT), (int)r.y);
    }
}

__global__ __launch_bounds__(256) void bucket_cw(
    const uint2* __restrict__ bktS, const int* __restrict__ baseS,
    float* __restrict__ cw, int N)
{
    const int b = blockIdx.x;
    const int lo = baseS[b], hi = baseS[b + 1];
    __shared__ float sm[NPB];
    const int tid = threadIdx.x;
    sm[2 * tid] = 0.f; sm[2 * tid + 1] = 0.f;
    __syncthreads();
    for (int i = lo + tid; i < hi; i += 256) {
        const uint2 r = bktS[i];
        atomicAdd(&sm[r.x], __uint_as_float(r.y));
    }
    __syncthreads();
    const int n0 = b * NPB + 2 * tid;
    if (n0 < N)     cw[n0]     = sm[2 * tid];
    if (n0 + 1 < N) cw[n0 + 1] = sm[2 * tid + 1];
}

// ---------------- fused aggregate + BN stats (v7b: XCD column-sliced) ----
// Block b: column-slice s = b&7 (16 bf16 cols = 8 uints = 32 B/row), node
// stripe t = b>>3 (64 nodes, 4 waves x 16). Row stride is 64 uints (128 bf16
// cols) — R9's stride-32 bug fixed. If dispatch round-robins XCDs, each
// XCD's blocks share one 3.2 MB h-slice -> L2-resident gathers.
#define AGG_R 16
__global__ __launch_bounds__(256) void aggregate5(
    const int2* __restrict__ packed, const int* __restrict__ rp,
    const unsigned* __restrict__ hu, unsigned* __restrict__ aggb,
    float* __restrict__ sum, float* __restrict__ sq, int N)
{
    const int tid = threadIdx.x;
    const int lane = tid & 63, wave = tid >> 6;
    const int slice = blockIdx.x & 7;          // 16-col slice
    const int stripe = blockIdx.x >> 3;        // 64-node stripe
    const int sub = lane >> 3;                 // octet 0..7 -> edge j+sub
    const int u = lane & 7;                    // uint within slice
    const int cpos = slice * 8 + u;            // uint col in row (of 64)
    const int n0 = (stripe * 4 + wave) * AGG_R;

    float2 csum = {0.f, 0.f}, csq = {0.f, 0.f};

    for (int r = 0; r < AGG_R; ++r) {
        const int n = n0 + r;
        if (n >= N) break;
        const int start = __builtin_amdgcn_readfirstlane((n == 0) ? 0 : rp[n - 1]);
        const int end   = __builtin_amdgcn_readfirstlane(rp[n]);
        float2 a = {0.f, 0.f};

        for (int base = start; base < end; base += 64) {
            const int cnt = min(64, end - base);
            int2 myE = make_int2(0, 0);
            if (lane < cnt) myE = packed[base + lane];
            for (int j = 0; j < cnt; j += 16) {     // 2 octet-groups (16 edges)
                const int i0 = j + sub, i1 = i0 + 8;
                const int c0 = (i0 < cnt) ? i0 : 0;
                const int c1 = (i1 < cnt) ? i1 : 0;
                const int s0 = __shfl(myE.x, c0, 64);
                const int s1 = __shfl(myE.x, c1, 64);
                float w0 = __uint_as_float((unsigned)__shfl(myE.y, c0, 64));
                float w1 = __uint_as_float((unsigned)__shfl(myE.y, c1, 64));
                if (i0 >= cnt) w0 = 0.f;
                if (i1 >= cnt) w1 = 0.f;
                const unsigned v0 = hu[(size_t)s0 * 64 + cpos];
                const unsigned v1 = hu[(size_t)s1 * 64 + cpos];
                a.x = fmaf(w0, blo(v0), a.x); a.y = fmaf(w0, bhi(v0), a.y);
                a.x = fmaf(w1, blo(v1), a.x); a.y = fmaf(w1, bhi(v1), a.y);
            }
        }
        // reduce across the 8 octets (lanes matching u differ in bits 3..5)
        a.x += __shfl_xor(a.x, 8, 64);  a.y += __shfl_xor(a.y, 8, 64);
        a.x += __shfl_xor(a.x, 16, 64); a.y += __shfl_xor(a.y, 16, 64);
        a.x += __shfl_xor(a.x, 32, 64); a.y += __shfl_xor(a.y, 32, 64);
        if (sub == 0) {
            aggb[(size_t)n * 64 + cpos] =
                (unsigned)f2bf(a.x) | ((unsigned)f2bf(a.y) << 16);
            csum.x += a.x; csum.y += a.y;
            csq.x = fmaf(a.x, a.x, csq.x);
            csq.y = fmaf(a.y, a.y, csq.y);
        }
    }

    __shared__ float lsum[64], lsq[64];   // [wave][col pair within slice]
    if (sub == 0) {
        lsum[wave * 16 + u * 2]     = csum.x;
        lsum[wave * 16 + u * 2 + 1] = csum.y;
        lsq[wave * 16 + u * 2]      = csq.x;
        lsq[wave * 16 + u * 2 + 1]  = csq.y;
    }
    __syncthreads();
    if (tid < 16) {
        const float s = lsum[tid] + lsum[16 + tid] + lsum[32 + tid] + lsum[48 + tid];
        const float q = lsq[tid] + lsq[16 + tid] + lsq[32 + tid] + lsq[48 + tid];
        const int col = slice * 16 + tid;
        const int sl = (stripe & (NSLICE - 1)) * 128;
        atomicAdd(&sum[sl + col], s);
        atomicAdd(&sq[sl + col], q);
    }
}

// ---------------- collapsed layer 2 (persistent grid, sliced-stat prologue) ----
__global__ __launch_bounds__(256) void wcolsum_bf16(
    const unsigned* __restrict__ xb, const float* __restrict__ cw,
    const float* __restrict__ sum1, const float* __restrict__ sq1,
    const float* __restrict__ g, const float* __restrict__ be,
    float* __restrict__ sout, int N)
{
    __shared__ float Aaf[128], Baf[128];
    __shared__ float2 ls[256];
    const int tid = threadIdx.x;
    if (tid < 128) {
        float s = 0.f, q = 0.f;
#pragma unroll
        for (int k = 0; k < NSLICE; ++k) {
            s += sum1[k * 128 + tid];
            q += sq1[k * 128 + tid];
        }
        const float invN = 1.0f / (float)N;
        const float m = s * invN;
        const float var = q * invN - m * m;
        const float rs = rsqrtf(var + BN_EPS);
        Aaf[tid] = g[tid] * rs;
        Baf[tid] = be[tid] - g[tid] * m * rs;
    }
    __syncthreads();
    const int u = tid & 63, rr = tid >> 6;
    const float ax = Aaf[2 * u], ay = Aaf[2 * u + 1];
    const float bx = Baf[2 * u], by = Baf[2 * u + 1];
    float2 s = {0.f, 0.f};
    for (int row = blockIdx.x * 4 + rr; row < N; row += gridDim.x * 4) {
        const unsigned v = xb[(size_t)row * 64 + u];
        const float c = cw[row];
        const float x = fmaxf(fmaf(ax, blo(v), bx), 0.f);
        const float y = fmaxf(fmaf(ay, bhi(v), by), 0.f);
        s.x = fmaf(c, x, s.x);
        s.y = fmaf(c, y, s.y);
    }
    ls[tid] = s;
    __syncthreads();
    if (tid < 64) {
        float sx = ls[tid].x + ls[64 + tid].x + ls[128 + tid].x + ls[192 + tid].x;
        float sy = ls[tid].y + ls[64 + tid].y + ls[128 + tid].y + ls[192 + tid].y;
        atomicAdd(&sout[2 * tid + 0], sx);
        atomicAdd(&sout[2 * tid + 1], sy);
    }
}

__global__ void final_out(
    const float* __restrict__ s, const float* __restrict__ W2,
    const float* __restrict__ b2, float* __restrict__ out, int N, int Dout)
{
    const int j = threadIdx.x;
    if (j < Dout) {
        float acc = 0.f;
        for (int f = 0; f < 128; ++f) acc = fmaf(s[f], W2[f * Dout + j], acc);
        out[j] = acc + (float)N * b2[j];
    }
}

extern "C" void kernel_launch(void* const* d_in, const int* in_sizes, int n_in,
                              void* d_out, int out_size, void* d_ws, size_t ws_size,
                              hipStream_t stream)
{
    const float* nf  = (const float*)d_in[0];
    const int*   ei  = (const int*)d_in[1];
    const float* ew  = (const float*)d_in[2];
    const float* W0  = (const float*)d_in[3];
    // b0 = d_in[4], b1 = d_in[6]: cancel inside BatchNorm, unused
    const float* W1  = (const float*)d_in[5];
    const float* W2  = (const float*)d_in[7];
    const float* b2  = (const float*)d_in[8];
    const float* g0  = (const float*)d_in[9];
    const float* be0 = (const float*)d_in[10];
    const float* g1  = (const float*)d_in[11];
    const float* be1 = (const float*)d_in[12];

    const int N = in_sizes[0] / 128;
    const int E = in_sizes[2];
    const int* srcI = ei;       // edge_index[0,:]
    const int* dstI = ei + E;   // edge_index[1,:]

    const int B = (N + NPB - 1) / NPB;        // 196 for N=100k
    const int chunk = (E + PB - 1) / PB;

    const size_t HB = ((size_t)N * 128 * 2 + 255) & ~(size_t)255;  // bf16 buf
    const size_t NA = ((size_t)N * sizeof(int) + 255) & ~(size_t)255;
    const size_t CB = (((size_t)B * PB * 4) + 255) & ~(size_t)255;
    char* ws = (char*)d_ws;
    size_t off = 0;
    float* cw    = (float*)(ws + off); off += NA;
    int*   rp    = (int*)  (ws + off); off += NA;
    float* stats = (float*)(ws + off); off += 36864;   // 4 sliced arrays + svec
    int*   cntD  = (int*)  (ws + off); off += CB;
    int*   cntS  = (int*)  (ws + off); off += CB;
    int*   baseD = (int*)  (ws + off); off += 2048;
    int*   baseS = (int*)  (ws + off); off += 2048;
    unsigned short* hbuf = (unsigned short*)(ws + off); off += HB;  // h (bf16)
    unsigned* aggb = (unsigned*)(ws + off); off += HB;              // agg (bf16)
    int2*  packed = (int2*)(ws + off); off += (size_t)E * 8;
    uint2* bktD  = (uint2*)(ws + off); off += (size_t)E * 8;
    uint2* bktS  = (uint2*)(ws + off); off += (size_t)E * 8;
    unsigned short* wt0 = (unsigned short*)(ws + off); off += 32768;
    unsigned short* wt1 = (unsigned short*)(ws + off); off += 32768;
    (void)ws_size;  // rounds 1-8 proved ws_size >= 116.5 MB; this needs ~92 MB

    // sliced stats: each array NSLICE*128 floats
    float* sum0 = stats + 0 * NSLICE * 128;
    float* sq0  = stats + 1 * NSLICE * 128;
    float* sum1 = stats + 2 * NSLICE * 128;
    float* sq1  = stats + 3 * NSLICE * 128;
    float* svec = stats + 4 * NSLICE * 128;   // [128]

    const int gemmGrid = (N + 63) / 64;
    const int aggGrid  = 8 * ((N + 63) / 64);   // 8 col-slices x node stripes

    hipMemsetAsync(stats, 0, (4 * NSLICE * 128 + 128) * sizeof(float), stream);

    // ---- atomic-free CSR build + cw (graph identical both layers) ----
    bucket_hist<<<PB, 256, 0, stream>>>(srcI, dstI, cntD, cntS, E, B, chunk);
    bucket_base<<<1, 256, 0, stream>>>(cntD, cntS, baseD, baseS, B, E);
    bucket_cursor<<<2 * B, 256, 0, stream>>>(cntD, cntS, baseD, baseS, B);
    bucket_place<<<PB, 256, 0, stream>>>(srcI, dstI, ew, cntD, cntS, bktD, bktS, E, B, chunk);
    bucket_sort<<<B, 256, 0, stream>>>(bktD, baseD, rp, packed, N);
    bucket_cw<<<B, 256, 0, stream>>>(bktS, baseS, cw, N);
    wconv<<<64, 256, 0, stream>>>(W0, W1, wt0, wt1);

    // ---- layer 0 ----
    gemm0<<<gemmGrid, 256, 0, stream>>>(nf, wt0, hbuf, N);
    aggregate5<<<aggGrid, 256, 0, stream>>>(
        packed, rp, (const unsigned*)hbuf, aggb, sum0, sq0, N);

    // ---- layer 1 (BN0+ReLU folded into GEMM staging) ----
    gemm1<<<gemmGrid, 256, 0, stream>>>(aggb, wt1, hbuf, sum0, sq0, g0, be0, N, N);
    aggregate5<<<aggGrid, 256, 0, stream>>>(
        packed, rp, (const unsigned*)hbuf, aggb, sum1, sq1, N);

    // ---- collapsed layer 2: out = (sum_n cw[n]*relu(BN1(x2))[n,:]) @ W2 + N*b2 ----
    wcolsum_bf16<<<256, 256, 0, stream>>>(aggb, cw, sum1, sq1, g1, be1, svec, N);
    final_out<<<1, 64, 0, stream>>>(svec, W2, b2, (float*)d_out, N, out_size);
}

// Round 11
// 464.304 us; speedup vs baseline: 1.5480x; 1.5480x over previous
//
#include <hip/hip_runtime.h>

#define BN_EPS 1e-5f

// Bucket-sort parameters: NPB nodes per bucket (pow2), PB placement blocks.
#define NPB 512
#define NPB_SHIFT 9
#define PB 512
#define MAXB 256
// BN-stat accumulator slices (atomic-depth reduction)
#define NSLICE 16

typedef __attribute__((ext_vector_type(8))) short short8;
typedef __attribute__((ext_vector_type(4))) float floatx4;

__device__ __forceinline__ unsigned short f2bf(float f) {
    unsigned u = __float_as_uint(f);
    unsigned r = u + 0x7FFFu + ((u >> 16) & 1u);   // round-to-nearest-even
    return (unsigned short)(r >> 16);
}
__device__ __forceinline__ float blo(unsigned v) { return __uint_as_float(v << 16); }
__device__ __forceinline__ float bhi(unsigned v) { return __uint_as_float(v & 0xffff0000u); }

// ------- W pre-transpose (+ stats zeroing folded in, saves a dispatch) -------
__global__ __launch_bounds__(256) void wconv(
    const float* __restrict__ W0, const float* __restrict__ W1,
    unsigned short* __restrict__ wt0, unsigned short* __restrict__ wt1,
    float* __restrict__ stats)
{
    const int idx = blockIdx.x * 256 + threadIdx.x;   // < 16384
    const int n = idx >> 7, k = idx & 127;
    wt0[idx] = f2bf(W0[k * 128 + n]);
    wt1[idx] = f2bf(W1[k * 128 + n]);
    if (blockIdx.x < 9) {   // zero 9216 floats (4 sliced stat arrays + svec)
        const int o = (blockIdx.x * 256 + threadIdx.x) * 4;
        *(float4*)&stats[o] = make_float4(0.f, 0.f, 0.f, 0.f);
    }
}

// ---------------- layer-0 GEMM: C[M x 128] = A_fp32 @ W ----------------
__global__ __launch_bounds__(256) void gemm0(
    const float* __restrict__ A, const unsigned short* __restrict__ Wt,
    unsigned short* __restrict__ C, int M)
{
    __shared__ char lds[53248];
    unsigned short* Al = (unsigned short*)lds;            // [64][136] bf16
    unsigned short* Wl = (unsigned short*)(lds + 17408);  // [128][136] bf16
    float* Cl = (float*)lds;                              // [64][132] f32 (reuse)

    const int tid = threadIdx.x;
    const int r0 = blockIdx.x * 64;

#pragma unroll
    for (int i = 0; i < 16; ++i) {
        const int idx = i * 256 + tid;          // ushort4 units
        const int n = idx >> 5, q = idx & 31;
        const ushort4 v = ((const ushort4*)Wt)[idx];
        *(ushort4*)&Wl[n * 136 + q * 4] = v;
    }
#pragma unroll
    for (int i = 0; i < 8; ++i) {
        const int row = i * 8 + (tid >> 5), q = tid & 31;
        const int gr = r0 + row;
        float4 v = (gr < M) ? ((const float4*)A)[(size_t)gr * 32 + q]
                            : make_float4(0.f, 0.f, 0.f, 0.f);
        ushort4 o;
        o.x = f2bf(v.x); o.y = f2bf(v.y); o.z = f2bf(v.z); o.w = f2bf(v.w);
        *(ushort4*)&Al[row * 136 + q * 4] = o;
    }
    __syncthreads();

    const int wave = tid >> 6, lane = tid & 63;
    const int lrow = lane & 15, quad = lane >> 4;
    const int n0 = wave * 32;

    floatx4 acc[4][2];
#pragma unroll
    for (int mt = 0; mt < 4; ++mt)
#pragma unroll
        for (int t = 0; t < 2; ++t)
#pragma unroll
            for (int j = 0; j < 4; ++j) acc[mt][t][j] = 0.f;

#pragma unroll
    for (int c = 0; c < 4; ++c) {
        const int k0 = c * 32;
        const short8 b0 = *(const short8*)&Wl[(n0 + lrow) * 136 + k0 + quad * 8];
        const short8 b1 = *(const short8*)&Wl[(n0 + 16 + lrow) * 136 + k0 + quad * 8];
#pragma unroll
        for (int mt = 0; mt < 4; ++mt) {
            const short8 a = *(const short8*)&Al[(mt * 16 + lrow) * 136 + k0 + quad * 8];
            acc[mt][0] = __builtin_amdgcn_mfma_f32_16x16x32_bf16(a, b0, acc[mt][0], 0, 0, 0);
            acc[mt][1] = __builtin_amdgcn_mfma_f32_16x16x32_bf16(a, b1, acc[mt][1], 0, 0, 0);
        }
    }
    __syncthreads();

#pragma unroll
    for (int mt = 0; mt < 4; ++mt)
#pragma unroll
        for (int t = 0; t < 2; ++t)
#pragma unroll
            for (int j = 0; j < 4; ++j)
                Cl[(mt * 16 + quad * 4 + j) * 132 + n0 + t * 16 + lrow] = acc[mt][t][j];
    __syncthreads();

#pragma unroll
    for (int i = 0; i < 4; ++i) {
        const int row = i * 16 + (tid >> 4);
        const int c0 = (tid & 15) * 8;
        const int gr = r0 + row;
        if (gr < M) {
            const float4 v0 = *(float4*)&Cl[row * 132 + c0];
            const float4 v1 = *(float4*)&Cl[row * 132 + c0 + 4];
            uint4 o;
            o.x = (unsigned)f2bf(v0.x) | ((unsigned)f2bf(v0.y) << 16);
            o.y = (unsigned)f2bf(v0.z) | ((unsigned)f2bf(v0.w) << 16);
            o.z = (unsigned)f2bf(v1.x) | ((unsigned)f2bf(v1.y) << 16);
            o.w = (unsigned)f2bf(v1.z) | ((unsigned)f2bf(v1.w) << 16);
            ((uint4*)C)[(size_t)gr * 16 + (c0 >> 3)] = o;
        }
    }
}

// ---------------- layer-1 GEMM: C = relu(BN(A_bf16)) @ W ----------------
// BN affine from SLICED raw stats (sum over NSLICE in prologue).
__global__ __launch_bounds__(256) void gemm1(
    const unsigned* __restrict__ Ab, const unsigned short* __restrict__ Wt,
    unsigned short* __restrict__ C,
    const float* __restrict__ sum, const float* __restrict__ sq,
    const float* __restrict__ g, const float* __restrict__ be,
    int M, int N)
{
    __shared__ char lds[53248];
    unsigned short* Al = (unsigned short*)lds;            // [64][136]
    unsigned short* Wl = (unsigned short*)(lds + 17408);  // [128][136]
    float* AscL = (float*)(lds + 52224);                  // [128]
    float* AshL = AscL + 128;
    float* Cl = (float*)lds;

    const int tid = threadIdx.x;
    const int r0 = blockIdx.x * 64;

    if (tid < 128) {
        float s = 0.f, q = 0.f;
#pragma unroll
        for (int k = 0; k < NSLICE; ++k) {
            s += sum[k * 128 + tid];
            q += sq[k * 128 + tid];
        }
        const float invN = 1.0f / (float)N;
        const float m = s * invN;
        const float var = q * invN - m * m;
        const float rs = rsqrtf(var + BN_EPS);
        AscL[tid] = g[tid] * rs;
        AshL[tid] = be[tid] - g[tid] * m * rs;
    }
    __syncthreads();

#pragma unroll
    for (int i = 0; i < 16; ++i) {
        const int idx = i * 256 + tid;
        const int n = idx >> 5, q = idx & 31;
        const ushort4 v = ((const ushort4*)Wt)[idx];
        *(ushort4*)&Wl[n * 136 + q * 4] = v;
    }
#pragma unroll
    for (int i = 0; i < 4; ++i) {
        const int idx = i * 256 + tid;
        const int row = idx >> 4, qc = idx & 15;
        const int gr = r0 + row;
        uint4 v = (gr < M) ? ((const uint4*)Ab)[(size_t)gr * 16 + qc]
                           : make_uint4(0, 0, 0, 0);
        const float4 a0 = *(const float4*)&AscL[qc * 8];
        const float4 a1 = *(const float4*)&AscL[qc * 8 + 4];
        const float4 b0 = *(const float4*)&AshL[qc * 8];
        const float4 b1 = *(const float4*)&AshL[qc * 8 + 4];
        float x0 = fmaxf(fmaf(a0.x, blo(v.x), b0.x), 0.f);
        float x1 = fmaxf(fmaf(a0.y, bhi(v.x), b0.y), 0.f);
        float x2 = fmaxf(fmaf(a0.z, blo(v.y), b0.z), 0.f);
        float x3 = fmaxf(fmaf(a0.w, bhi(v.y), b0.w), 0.f);
        float x4 = fmaxf(fmaf(a1.x, blo(v.z), b1.x), 0.f);
        float x5 = fmaxf(fmaf(a1.y, bhi(v.z), b1.y), 0.f);
        float x6 = fmaxf(fmaf(a1.z, blo(v.w), b1.z), 0.f);
        float x7 = fmaxf(fmaf(a1.w, bhi(v.w), b1.w), 0.f);
        uint4 o;
        o.x = (unsigned)f2bf(x0) | ((unsigned)f2bf(x1) << 16);
        o.y = (unsigned)f2bf(x2) | ((unsigned)f2bf(x3) << 16);
        o.z = (unsigned)f2bf(x4) | ((unsigned)f2bf(x5) << 16);
        o.w = (unsigned)f2bf(x6) | ((unsigned)f2bf(x7) << 16);
        *(uint4*)&Al[row * 136 + qc * 8] = o;
    }
    __syncthreads();

    const int wave = tid >> 6, lane = tid & 63;
    const int lrow = lane & 15, quad = lane >> 4;
    const int n0 = wave * 32;

    floatx4 acc[4][2];
#pragma unroll
    for (int mt = 0; mt < 4; ++mt)
#pragma unroll
        for (int t = 0; t < 2; ++t)
#pragma unroll
            for (int j = 0; j < 4; ++j) acc[mt][t][j] = 0.f;

#pragma unroll
    for (int c = 0; c < 4; ++c) {
        const int k0 = c * 32;
        const short8 b0 = *(const short8*)&Wl[(n0 + lrow) * 136 + k0 + quad * 8];
        const short8 b1 = *(const short8*)&Wl[(n0 + 16 + lrow) * 136 + k0 + quad * 8];
#pragma unroll
        for (int mt = 0; mt < 4; ++mt) {
            const short8 a = *(const short8*)&Al[(mt * 16 + lrow) * 136 + k0 + quad * 8];
            acc[mt][0] = __builtin_amdgcn_mfma_f32_16x16x32_bf16(a, b0, acc[mt][0], 0, 0, 0);
            acc[mt][1] = __builtin_amdgcn_mfma_f32_16x16x32_bf16(a, b1, acc[mt][1], 0, 0, 0);
        }
    }
    __syncthreads();

#pragma unroll
    for (int mt = 0; mt < 4; ++mt)
#pragma unroll
        for (int t = 0; t < 2; ++t)
#pragma unroll
            for (int j = 0; j < 4; ++j)
                Cl[(mt * 16 + quad * 4 + j) * 132 + n0 + t * 16 + lrow] = acc[mt][t][j];
    __syncthreads();

#pragma unroll
    for (int i = 0; i < 4; ++i) {
        const int row = i * 16 + (tid >> 4);
        const int c0 = (tid & 15) * 8;
        const int gr = r0 + row;
        if (gr < M) {
            const float4 v0 = *(float4*)&Cl[row * 132 + c0];
            const float4 v1 = *(float4*)&Cl[row * 132 + c0 + 4];
            uint4 o;
            o.x = (unsigned)f2bf(v0.x) | ((unsigned)f2bf(v0.y) << 16);
            o.y = (unsigned)f2bf(v0.z) | ((unsigned)f2bf(v0.w) << 16);
            o.z = (unsigned)f2bf(v1.x) | ((unsigned)f2bf(v1.y) << 16);
            o.w = (unsigned)f2bf(v1.z) | ((unsigned)f2bf(v1.w) << 16);
            ((uint4*)C)[(size_t)gr * 16 + (c0 >> 3)] = o;
        }
    }
}

// ============ atomic-free CSR build: two-level bucket counting sort ============

__global__ __launch_bounds__(256) void bucket_hist(
    const int* __restrict__ src, const int* __restrict__ dst,
    int* __restrict__ cntD, int* __restrict__ cntS, int E, int B, int chunk)
{
    __shared__ int hD[MAXB], hS[MAXB];
    const int tid = threadIdx.x;
    for (int i = tid; i < B; i += 256) { hD[i] = 0; hS[i] = 0; }
    __syncthreads();
    const int lo = blockIdx.x * chunk;
    const int hi = min(E, lo + chunk);
    for (int e = lo + tid; e < hi; e += 256) {
        atomicAdd(&hD[dst[e] >> NPB_SHIFT], 1);
        atomicAdd(&hS[src[e] >> NPB_SHIFT], 1);
    }
    __syncthreads();
    for (int i = tid; i < B; i += 256) {
        cntD[i * PB + blockIdx.x] = hD[i];
        cntS[i * PB + blockIdx.x] = hS[i];
    }
}

__global__ __launch_bounds__(256) void bucket_base(
    const int* __restrict__ cntD, const int* __restrict__ cntS,
    int* __restrict__ baseD, int* __restrict__ baseS, int B, int E)
{
    __shared__ int lD[256], lS[256];
    const int tid = threadIdx.x;
    int sD = 0, sS = 0;
    if (tid < B) {
        const int4* pD = (const int4*)(cntD + tid * PB);
        const int4* pS = (const int4*)(cntS + tid * PB);
        for (int j = 0; j < PB / 4; ++j) {
            const int4 a = pD[j], b = pS[j];
            sD += a.x + a.y + a.z + a.w;
            sS += b.x + b.y + b.z + b.w;
        }
    }
    lD[tid] = sD; lS[tid] = sS;
    __syncthreads();
    for (int st = 1; st < 256; st <<= 1) {
        const int vD = (tid >= st) ? lD[tid - st] : 0;
        const int vS = (tid >= st) ? lS[tid - st] : 0;
        __syncthreads();
        lD[tid] += vD; lS[tid] += vS;
        __syncthreads();
    }
    if (tid < B) { baseD[tid] = lD[tid] - sD; baseS[tid] = lS[tid] - sS; }
    if (tid == 0) { baseD[B] = E; baseS[B] = E; }
}

__global__ __launch_bounds__(256) void bucket_cursor(
    int* __restrict__ cntD, int* __restrict__ cntS,
    const int* __restrict__ baseD, const int* __restrict__ baseS, int B)
{
    int b = blockIdx.x;
    int* cnt; const int* base;
    if (b < B) { cnt = cntD; base = baseD; }
    else       { cnt = cntS; base = baseS; b -= B; }
    __shared__ int ls[256];
    const int tid = threadIdx.x;
    const int c0 = cnt[b * PB + 2 * tid];
    const int c1 = cnt[b * PB + 2 * tid + 1];
    const int s = c0 + c1;
    ls[tid] = s;
    __syncthreads();
    for (int st = 1; st < 256; st <<= 1) {
        const int v = (tid >= st) ? ls[tid - st] : 0;
        __syncthreads();
        ls[tid] += v;
        __syncthreads();
    }
    const int excl = ls[tid] - s + base[b];
    cnt[b * PB + 2 * tid] = excl;
    cnt[b * PB + 2 * tid + 1] = excl + c0;
}

__global__ __launch_bounds__(256) void bucket_place(
    const int* __restrict__ src, const int* __restrict__ dst,
    const float* __restrict__ ew,
    const int* __restrict__ curD, const int* __restrict__ curS,
    uint2* __restrict__ bktD, uint2* __restrict__ bktS, int E, int B, int chunk)
{
    __shared__ int cD[MAXB], cS[MAXB];
    const int tid = threadIdx.x;
    for (int i = tid; i < B; i += 256) {
        cD[i] = curD[i * PB + blockIdx.x];
        cS[i] = curS[i * PB + blockIdx.x];
    }
    __syncthreads();
    const int lo = blockIdx.x * chunk;
    const int hi = min(E, lo + chunk);
    for (int e = lo + tid; e < hi; e += 256) {
        const int s = src[e], d = dst[e];
        const unsigned wb = __float_as_uint(ew[e]);
        const int pd = atomicAdd(&cD[d >> NPB_SHIFT], 1);
        bktD[pd] = make_uint2(((unsigned)s << NPB_SHIFT) | (unsigned)(d & (NPB - 1)), wb);
        const int ps = atomicAdd(&cS[s >> NPB_SHIFT], 1);
        bktS[ps] = make_uint2((unsigned)(s & (NPB - 1)), wb);
    }
}

__global__ __launch_bounds__(256) void bucket_sort(
    const uint2* __restrict__ bktD, const int* __restrict__ baseD,
    int* __restrict__ rp, int2* __restrict__ packed, int N)
{
    const int b = blockIdx.x;
    const int lo = baseD[b], hi = baseD[b + 1];
    __shared__ int cnt[NPB], cur[NPB];
    __shared__ int ls[256];
    const int tid = threadIdx.x;
    cnt[2 * tid] = 0; cnt[2 * tid + 1] = 0;
    __syncthreads();
    for (int i = lo + tid; i < hi; i += 256)
        atomicAdd(&cnt[bktD[i].x & (NPB - 1)], 1);
    __syncthreads();
    const int c0 = cnt[2 * tid], c1 = cnt[2 * tid + 1];
    const int s = c0 + c1;
    ls[tid] = s;
    __syncthreads();
    for (int st = 1; st < 256; st <<= 1) {
        const int v = (tid >= st) ? ls[tid - st] : 0;
        __syncthreads();
        ls[tid] += v;
        __syncthreads();
    }
    const int excl = ls[tid] - s;
    const int n0 = b * NPB + 2 * tid;
    if (n0 < N)     rp[n0]     = lo + excl + c0;
    if (n0 + 1 < N) rp[n0 + 1] = lo + excl + c0 + c1;
    cur[2 * tid]     = lo + excl;
    cur[2 * tid + 1] = lo + excl + c0;
    __syncthreads();
    for (int i = lo + tid; i < hi; i += 256) {
        const uint2 r = bktD[i];
        const int pos = atomicAdd(&cur[r.x & (NPB - 1)], 1);
        packed[pos] = make_int2((int)(r.x >> NPB_SHIFT), (int)r.y);
    }
}

__global__ __launch_bounds__(256) void bucket_cw(
    const uint2* __restrict__ bktS, const int* __restrict__ baseS,
    float* __restrict__ cw, int N)
{
    const int b = blockIdx.x;
    const int lo = baseS[b], hi = baseS[b + 1];
    __shared__ float sm[NPB];
    const int tid = threadIdx.x;
    sm[2 * tid] = 0.f; sm[2 * tid + 1] = 0.f;
    __syncthreads();
    for (int i = lo + tid; i < hi; i += 256) {
        const uint2 r = bktS[i];
        atomicAdd(&sm[r.x], __uint_as_float(r.y));
    }
    __syncthreads();
    const int n0 = b * NPB + 2 * tid;
    if (n0 < N)     cw[n0]     = sm[2 * tid];
    if (n0 + 1 < N) cw[n0 + 1] = sm[2 * tid + 1];
}

// ------- fused aggregate + BN stats (v8: R8 structure + rp/edge prefetch) ----
// R8-proven: quarter-wave uint4 gathers, wide grid, NSLICE-sliced stats.
// New: (1) the wave's 17 row-pointers are contiguous -> ONE coalesced load
// (rpv) + __shfl, deleting 2 dependent global loads per node; (2) node r+1's
// first edge chunk is prefetched during node r's gathers (start known from
// rpv), overlapping the packed load with the gather latency.
#define AGG_R 16
__global__ __launch_bounds__(256) void aggregate4(
    const int2* __restrict__ packed, const int* __restrict__ rp,
    const uint4* __restrict__ h4, uint4* __restrict__ aggb4,
    float* __restrict__ sum, float* __restrict__ sq, int N)
{
    const int tid = threadIdx.x;
    const int lane = tid & 63, wave = tid >> 6;
    const int sub = lane >> 4;          // quarter 0..3 -> edge j+sub
    const int u = lane & 15;            // cols 8u..8u+7 (uint4)
    const int n0 = (blockIdx.x * 4 + wave) * AGG_R;

    // coalesced row-pointer block: lane l holds rp[n0-1+l], l in [0,16]
    int rpv = 0;
    {
        const int idx = n0 - 1 + lane;
        if (lane <= AGG_R && idx >= 0 && idx < N) rpv = rp[idx];
    }

    float csum[8], csq[8];
#pragma unroll
    for (int k = 0; k < 8; ++k) { csum[k] = 0.f; csq[k] = 0.f; }

    // prefetch node 0's first edge chunk
    int2 curE = make_int2(0, 0);
    if (n0 < N) {
        const int s0 = __shfl(rpv, 0, 64), e0 = __shfl(rpv, 1, 64);
        if (lane < min(64, e0 - s0)) curE = packed[s0 + lane];
    }

    for (int r = 0; r < AGG_R; ++r) {
        const int n = n0 + r;
        if (n >= N) break;
        const int start = __shfl(rpv, r, 64);
        const int end   = __shfl(rpv, r + 1, 64);

        // prefetch next node's first chunk (overlaps this node's gathers)
        int2 nextE = make_int2(0, 0);
        if (r + 1 < AGG_R && n + 1 < N) {
            const int ns = __shfl(rpv, r + 1, 64), ne = __shfl(rpv, r + 2, 64);
            if (lane < min(64, ne - ns)) nextE = packed[ns + lane];
        }

        float a[8];
#pragma unroll
        for (int k = 0; k < 8; ++k) a[k] = 0.f;

        for (int base = start; base < end; base += 64) {
            const int cnt = min(64, end - base);
            int2 myE;
            if (base == start) {
                myE = curE;
            } else {
                myE = make_int2(0, 0);
                if (lane < cnt) myE = packed[base + lane];
            }
            for (int j = 0; j < cnt; j += 16) {
                const int i0 = j + sub, i1 = i0 + 4, i2 = i0 + 8, i3 = i0 + 12;
                const int c0 = (i0 < cnt) ? i0 : 0;
                const int c1 = (i1 < cnt) ? i1 : 0;
                const int c2 = (i2 < cnt) ? i2 : 0;
                const int c3 = (i3 < cnt) ? i3 : 0;
                const int s0 = __shfl(myE.x, c0, 64);
                const int s1 = __shfl(myE.x, c1, 64);
                const int s2 = __shfl(myE.x, c2, 64);
                const int s3 = __shfl(myE.x, c3, 64);
                float w0 = __uint_as_float((unsigned)__shfl(myE.y, c0, 64));
                float w1 = __uint_as_float((unsigned)__shfl(myE.y, c1, 64));
                float w2 = __uint_as_float((unsigned)__shfl(myE.y, c2, 64));
                float w3 = __uint_as_float((unsigned)__shfl(myE.y, c3, 64));
                if (i0 >= cnt) w0 = 0.f;
                if (i1 >= cnt) w1 = 0.f;
                if (i2 >= cnt) w2 = 0.f;
                if (i3 >= cnt) w3 = 0.f;
                const uint4 v0 = h4[(size_t)s0 * 16 + u];
                const uint4 v1 = h4[(size_t)s1 * 16 + u];
                const uint4 v2 = h4[(size_t)s2 * 16 + u];
                const uint4 v3 = h4[(size_t)s3 * 16 + u];
                a[0] = fmaf(w0, blo(v0.x), a[0]); a[1] = fmaf(w0, bhi(v0.x), a[1]);
                a[2] = fmaf(w0, blo(v0.y), a[2]); a[3] = fmaf(w0, bhi(v0.y), a[3]);
                a[4] = fmaf(w0, blo(v0.z), a[4]); a[5] = fmaf(w0, bhi(v0.z), a[5]);
                a[6] = fmaf(w0, blo(v0.w), a[6]); a[7] = fmaf(w0, bhi(v0.w), a[7]);
                a[0] = fmaf(w1, blo(v1.x), a[0]); a[1] = fmaf(w1, bhi(v1.x), a[1]);
                a[2] = fmaf(w1, blo(v1.y), a[2]); a[3] = fmaf(w1, bhi(v1.y), a[3]);
                a[4] = fmaf(w1, blo(v1.z), a[4]); a[5] = fmaf(w1, bhi(v1.z), a[5]);
                a[6] = fmaf(w1, blo(v1.w), a[6]); a[7] = fmaf(w1, bhi(v1.w), a[7]);
                a[0] = fmaf(w2, blo(v2.x), a[0]); a[1] = fmaf(w2, bhi(v2.x), a[1]);
                a[2] = fmaf(w2, blo(v2.y), a[2]); a[3] = fmaf(w2, bhi(v2.y), a[3]);
                a[4] = fmaf(w2, blo(v2.z), a[4]); a[5] = fmaf(w2, bhi(v2.z), a[5]);
                a[6] = fmaf(w2, blo(v2.w), a[6]); a[7] = fmaf(w2, bhi(v2.w), a[7]);
                a[0] = fmaf(w3, blo(v3.x), a[0]); a[1] = fmaf(w3, bhi(v3.x), a[1]);
                a[2] = fmaf(w3, blo(v3.y), a[2]); a[3] = fmaf(w3, bhi(v3.y), a[3]);
                a[4] = fmaf(w3, blo(v3.z), a[4]); a[5] = fmaf(w3, bhi(v3.z), a[5]);
                a[6] = fmaf(w3, blo(v3.w), a[6]); a[7] = fmaf(w3, bhi(v3.w), a[7]);
            }
        }
        // reduce across the 4 quarter-waves
#pragma unroll
        for (int k = 0; k < 8; ++k) {
            a[k] += __shfl_xor(a[k], 16, 64);
            a[k] += __shfl_xor(a[k], 32, 64);
        }
        if (sub == 0) {
            uint4 o;
            o.x = (unsigned)f2bf(a[0]) | ((unsigned)f2bf(a[1]) << 16);
            o.y = (unsigned)f2bf(a[2]) | ((unsigned)f2bf(a[3]) << 16);
            o.z = (unsigned)f2bf(a[4]) | ((unsigned)f2bf(a[5]) << 16);
            o.w = (unsigned)f2bf(a[6]) | ((unsigned)f2bf(a[7]) << 16);
            aggb4[(size_t)n * 16 + u] = o;
#pragma unroll
            for (int k = 0; k < 8; ++k) {
                csum[k] += a[k];
                csq[k] = fmaf(a[k], a[k], csq[k]);
            }
        }
        curE = nextE;
    }

    __shared__ float lsum[512], lsq[512];   // [wave][col=u*8+k]
    if (sub == 0) {
#pragma unroll
        for (int k = 0; k < 8; ++k) {
            lsum[wave * 128 + u * 8 + k] = csum[k];
            lsq[wave * 128 + u * 8 + k] = csq[k];
        }
    }
    __syncthreads();
    if (tid < 128) {
        const float s = lsum[tid] + lsum[128 + tid] + lsum[256 + tid] + lsum[384 + tid];
        const float q = lsq[tid] + lsq[128 + tid] + lsq[256 + tid] + lsq[384 + tid];
        const int sl = (blockIdx.x & (NSLICE - 1)) * 128;
        atomicAdd(&sum[sl + tid], s);
        atomicAdd(&sq[sl + tid], q);
    }
}

// ---------------- collapsed layer 2 (persistent grid, sliced-stat prologue) ----
__global__ __launch_bounds__(256) void wcolsum_bf16(
    const unsigned* __restrict__ xb, const float* __restrict__ cw,
    const float* __restrict__ sum1, const float* __restrict__ sq1,
    const float* __restrict__ g, const float* __restrict__ be,
    float* __restrict__ sout, int N)
{
    __shared__ float Aaf[128], Baf[128];
    __shared__ float2 ls[256];
    const int tid = threadIdx.x;
    if (tid < 128) {
        float s = 0.f, q = 0.f;
#pragma unroll
        for (int k = 0; k < NSLICE; ++k) {
            s += sum1[k * 128 + tid];
            q += sq1[k * 128 + tid];
        }
        const float invN = 1.0f / (float)N;
        const float m = s * invN;
        const float var = q * invN - m * m;
        const float rs = rsqrtf(var + BN_EPS);
        Aaf[tid] = g[tid] * rs;
        Baf[tid] = be[tid] - g[tid] * m * rs;
    }
    __syncthreads();
    const int u = tid & 63, rr = tid >> 6;
    const float ax = Aaf[2 * u], ay = Aaf[2 * u + 1];
    const float bx = Baf[2 * u], by = Baf[2 * u + 1];
    float2 s = {0.f, 0.f};
    for (int row = blockIdx.x * 4 + rr; row < N; row += gridDim.x * 4) {
        const unsigned v = xb[(size_t)row * 64 + u];
        const float c = cw[row];
        const float x = fmaxf(fmaf(ax, blo(v), bx), 0.f);
        const float y = fmaxf(fmaf(ay, bhi(v), by), 0.f);
        s.x = fmaf(c, x, s.x);
        s.y = fmaf(c, y, s.y);
    }
    ls[tid] = s;
    __syncthreads();
    if (tid < 64) {
        float sx = ls[tid].x + ls[64 + tid].x + ls[128 + tid].x + ls[192 + tid].x;
        float sy = ls[tid].y + ls[64 + tid].y + ls[128 + tid].y + ls[192 + tid].y;
        atomicAdd(&sout[2 * tid + 0], sx);
        atomicAdd(&sout[2 * tid + 1], sy);
    }
}

__global__ void final_out(
    const float* __restrict__ s, const float* __restrict__ W2,
    const float* __restrict__ b2, float* __restrict__ out, int N, int Dout)
{
    const int j = threadIdx.x;
    if (j < Dout) {
        float acc = 0.f;
        for (int f = 0; f < 128; ++f) acc = fmaf(s[f], W2[f * Dout + j], acc);
        out[j] = acc + (float)N * b2[j];
    }
}

extern "C" void kernel_launch(void* const* d_in, const int* in_sizes, int n_in,
                              void* d_out, int out_size, void* d_ws, size_t ws_size,
                              hipStream_t stream)
{
    const float* nf  = (const float*)d_in[0];
    const int*   ei  = (const int*)d_in[1];
    const float* ew  = (const float*)d_in[2];
    const float* W0  = (const float*)d_in[3];
    // b0 = d_in[4], b1 = d_in[6]: cancel inside BatchNorm, unused
    const float* W1  = (const float*)d_in[5];
    const float* W2  = (const float*)d_in[7];
    const float* b2  = (const float*)d_in[8];
    const float* g0  = (const float*)d_in[9];
    const float* be0 = (const float*)d_in[10];
    const float* g1  = (const float*)d_in[11];
    const float* be1 = (const float*)d_in[12];

    const int N = in_sizes[0] / 128;
    const int E = in_sizes[2];
    const int* srcI = ei;       // edge_index[0,:]
    const int* dstI = ei + E;   // edge_index[1,:]

    const int B = (N + NPB - 1) / NPB;        // 196 for N=100k
    const int chunk = (E + PB - 1) / PB;

    const size_t HB = ((size_t)N * 128 * 2 + 255) & ~(size_t)255;  // bf16 buf
    const size_t NA = ((size_t)N * sizeof(int) + 255) & ~(size_t)255;
    const size_t CB = (((size_t)B * PB * 4) + 255) & ~(size_t)255;
    char* ws = (char*)d_ws;
    size_t off = 0;
    float* cw    = (float*)(ws + off); off += NA;
    int*   rp    = (int*)  (ws + off); off += NA;
    float* stats = (float*)(ws + off); off += 36864;   // 4 sliced arrays + svec
    int*   cntD  = (int*)  (ws + off); off += CB;
    int*   cntS  = (int*)  (ws + off); off += CB;
    int*   baseD = (int*)  (ws + off); off += 2048;
    int*   baseS = (int*)  (ws + off); off += 2048;
    unsigned short* hbuf = (unsigned short*)(ws + off); off += HB;  // h (bf16)
    unsigned* aggb = (unsigned*)(ws + off); off += HB;              // agg (bf16)
    int2*  packed = (int2*)(ws + off); off += (size_t)E * 8;
    uint2* bktD  = (uint2*)(ws + off); off += (size_t)E * 8;
    uint2* bktS  = (uint2*)(ws + off); off += (size_t)E * 8;
    unsigned short* wt0 = (unsigned short*)(ws + off); off += 32768;
    unsigned short* wt1 = (unsigned short*)(ws + off); off += 32768;
    (void)ws_size;  // rounds 1-10 proved ws_size >= 116.5 MB; this needs ~92 MB

    // sliced stats: each array NSLICE*128 floats
    float* sum0 = stats + 0 * NSLICE * 128;
    float* sq0  = stats + 1 * NSLICE * 128;
    float* sum1 = stats + 2 * NSLICE * 128;
    float* sq1  = stats + 3 * NSLICE * 128;
    float* svec = stats + 4 * NSLICE * 128;   // [128]

    const int gemmGrid = (N + 63) / 64;
    const int aggGrid  = (N + 4 * AGG_R - 1) / (4 * AGG_R);   // 1563

    // ---- atomic-free CSR build + cw (graph identical both layers) ----
    bucket_hist<<<PB, 256, 0, stream>>>(srcI, dstI, cntD, cntS, E, B, chunk);
    bucket_base<<<1, 256, 0, stream>>>(cntD, cntS, baseD, baseS, B, E);
    bucket_cursor<<<2 * B, 256, 0, stream>>>(cntD, cntS, baseD, baseS, B);
    bucket_place<<<PB, 256, 0, stream>>>(srcI, dstI, ew, cntD, cntS, bktD, bktS, E, B, chunk);
    bucket_sort<<<B, 256, 0, stream>>>(bktD, baseD, rp, packed, N);
    bucket_cw<<<B, 256, 0, stream>>>(bktS, baseS, cw, N);
    wconv<<<64, 256, 0, stream>>>(W0, W1, wt0, wt1, stats);   // + stats zeroing

    // ---- layer 0 ----
    gemm0<<<gemmGrid, 256, 0, stream>>>(nf, wt0, hbuf, N);
    aggregate4<<<aggGrid, 256, 0, stream>>>(
        packed, rp, (const uint4*)hbuf, (uint4*)aggb, sum0, sq0, N);

    // ---- layer 1 (BN0+ReLU folded into GEMM staging) ----
    gemm1<<<gemmGrid, 256, 0, stream>>>(aggb, wt1, hbuf, sum0, sq0, g0, be0, N, N);
    aggregate4<<<aggGrid, 256, 0, stream>>>(
        packed, rp, (const uint4*)hbuf, (uint4*)aggb, sum1, sq1, N);

    // ---- collapsed layer 2: out = (sum_n cw[n]*relu(BN1(x2))[n,:]) @ W2 + N*b2 ----
    wcolsum_bf16<<<256, 256, 0, stream>>>(aggb, cw, sum1, sq1, g1, be1, svec, N);
    final_out<<<1, 64, 0, stream>>>(svec, W2, b2, (float*)d_out, N, out_size);
}

// Round 12
// 420.513 us; speedup vs baseline: 1.7092x; 1.1041x over previous
//
#include <hip/hip_runtime.h>

#define BN_EPS 1e-5f

// Bucket-sort parameters: NPB nodes per bucket (pow2), PB placement blocks.
#define NPB 512
#define NPB_SHIFT 9
#define PB 512
#define MAXB 256
// BN-stat accumulator slices (atomic-depth reduction)
#define NSLICE 16

typedef __attribute__((ext_vector_type(8))) short short8;
typedef __attribute__((ext_vector_type(4))) float floatx4;
typedef __attribute__((ext_vector_type(2))) float floatx2;

__device__ __forceinline__ unsigned short f2bf(float f) {
    unsigned u = __float_as_uint(f);
    unsigned r = u + 0x7FFFu + ((u >> 16) & 1u);   // round-to-nearest-even
    return (unsigned short)(r >> 16);
}
__device__ __forceinline__ float blo(unsigned v) { return __uint_as_float(v << 16); }
__device__ __forceinline__ float bhi(unsigned v) { return __uint_as_float(v & 0xffff0000u); }

// pack 8 fp32 -> 8 fp8 e4m3 (2 dwords); byte k of output = value k
__device__ __forceinline__ uint2 pk8_fp8(const float4 v0, const float4 v1) {
    int lo = 0, hi = 0;
    lo = __builtin_amdgcn_cvt_pk_fp8_f32(v0.x, v0.y, lo, false);
    lo = __builtin_amdgcn_cvt_pk_fp8_f32(v0.z, v0.w, lo, true);
    hi = __builtin_amdgcn_cvt_pk_fp8_f32(v1.x, v1.y, hi, false);
    hi = __builtin_amdgcn_cvt_pk_fp8_f32(v1.z, v1.w, hi, true);
    return make_uint2((unsigned)lo, (unsigned)hi);
}

// ------- W pre-transpose (+ stats zeroing folded in, saves a dispatch) -------
__global__ __launch_bounds__(256) void wconv(
    const float* __restrict__ W0, const float* __restrict__ W1,
    unsigned short* __restrict__ wt0, unsigned short* __restrict__ wt1,
    float* __restrict__ stats)
{
    const int idx = blockIdx.x * 256 + threadIdx.x;   // < 16384
    const int n = idx >> 7, k = idx & 127;
    wt0[idx] = f2bf(W0[k * 128 + n]);
    wt1[idx] = f2bf(W1[k * 128 + n]);
    if (blockIdx.x < 9) {   // zero 9216 floats (4 sliced stat arrays + svec)
        const int o = (blockIdx.x * 256 + threadIdx.x) * 4;
        *(float4*)&stats[o] = make_float4(0.f, 0.f, 0.f, 0.f);
    }
}

// ------- layer-0 GEMM: C[M x 128] = A_fp32 @ W, C in fp8 e4m3 -------
__global__ __launch_bounds__(256) void gemm0(
    const float* __restrict__ A, const unsigned short* __restrict__ Wt,
    uint2* __restrict__ C, int M)
{
    __shared__ char lds[53248];
    unsigned short* Al = (unsigned short*)lds;            // [64][136] bf16
    unsigned short* Wl = (unsigned short*)(lds + 17408);  // [128][136] bf16
    float* Cl = (float*)lds;                              // [64][132] f32 (reuse)

    const int tid = threadIdx.x;
    const int r0 = blockIdx.x * 64;

#pragma unroll
    for (int i = 0; i < 16; ++i) {
        const int idx = i * 256 + tid;          // ushort4 units
        const int n = idx >> 5, q = idx & 31;
        const ushort4 v = ((const ushort4*)Wt)[idx];
        *(ushort4*)&Wl[n * 136 + q * 4] = v;
    }
#pragma unroll
    for (int i = 0; i < 8; ++i) {
        const int row = i * 8 + (tid >> 5), q = tid & 31;
        const int gr = r0 + row;
        float4 v = (gr < M) ? ((const float4*)A)[(size_t)gr * 32 + q]
                            : make_float4(0.f, 0.f, 0.f, 0.f);
        ushort4 o;
        o.x = f2bf(v.x); o.y = f2bf(v.y); o.z = f2bf(v.z); o.w = f2bf(v.w);
        *(ushort4*)&Al[row * 136 + q * 4] = o;
    }
    __syncthreads();

    const int wave = tid >> 6, lane = tid & 63;
    const int lrow = lane & 15, quad = lane >> 4;
    const int n0 = wave * 32;

    floatx4 acc[4][2];
#pragma unroll
    for (int mt = 0; mt < 4; ++mt)
#pragma unroll
        for (int t = 0; t < 2; ++t)
#pragma unroll
            for (int j = 0; j < 4; ++j) acc[mt][t][j] = 0.f;

#pragma unroll
    for (int c = 0; c < 4; ++c) {
        const int k0 = c * 32;
        const short8 b0 = *(const short8*)&Wl[(n0 + lrow) * 136 + k0 + quad * 8];
        const short8 b1 = *(const short8*)&Wl[(n0 + 16 + lrow) * 136 + k0 + quad * 8];
#pragma unroll
        for (int mt = 0; mt < 4; ++mt) {
            const short8 a = *(const short8*)&Al[(mt * 16 + lrow) * 136 + k0 + quad * 8];
            acc[mt][0] = __builtin_amdgcn_mfma_f32_16x16x32_bf16(a, b0, acc[mt][0], 0, 0, 0);
            acc[mt][1] = __builtin_amdgcn_mfma_f32_16x16x32_bf16(a, b1, acc[mt][1], 0, 0, 0);
        }
    }
    __syncthreads();

#pragma unroll
    for (int mt = 0; mt < 4; ++mt)
#pragma unroll
        for (int t = 0; t < 2; ++t)
#pragma unroll
            for (int j = 0; j < 4; ++j)
                Cl[(mt * 16 + quad * 4 + j) * 132 + n0 + t * 16 + lrow] = acc[mt][t][j];
    __syncthreads();

#pragma unroll
    for (int i = 0; i < 4; ++i) {
        const int row = i * 16 + (tid >> 4);
        const int c0 = (tid & 15) * 8;
        const int gr = r0 + row;
        if (gr < M) {
            const float4 v0 = *(float4*)&Cl[row * 132 + c0];
            const float4 v1 = *(float4*)&Cl[row * 132 + c0 + 4];
            C[(size_t)gr * 16 + (c0 >> 3)] = pk8_fp8(v0, v1);
        }
    }
}

// ------- layer-1 GEMM: C = relu(BN(A_bf16)) @ W, C in fp8 e4m3 -------
// BN affine from SLICED raw stats (sum over NSLICE in prologue).
__global__ __launch_bounds__(256) void gemm1(
    const unsigned* __restrict__ Ab, const unsigned short* __restrict__ Wt,
    uint2* __restrict__ C,
    const float* __restrict__ sum, const float* __restrict__ sq,
    const float* __restrict__ g, const float* __restrict__ be,
    int M, int N)
{
    __shared__ char lds[53248];
    unsigned short* Al = (unsigned short*)lds;            // [64][136]
    unsigned short* Wl = (unsigned short*)(lds + 17408);  // [128][136]
    float* AscL = (float*)(lds + 52224);                  // [128]
    float* AshL = AscL + 128;
    float* Cl = (float*)lds;

    const int tid = threadIdx.x;
    const int r0 = blockIdx.x * 64;

    if (tid < 128) {
        float s = 0.f, q = 0.f;
#pragma unroll
        for (int k = 0; k < NSLICE; ++k) {
            s += sum[k * 128 + tid];
            q += sq[k * 128 + tid];
        }
        const float invN = 1.0f / (float)N;
        const float m = s * invN;
        const float var = q * invN - m * m;
        const float rs = rsqrtf(var + BN_EPS);
        AscL[tid] = g[tid] * rs;
        AshL[tid] = be[tid] - g[tid] * m * rs;
    }
    __syncthreads();

#pragma unroll
    for (int i = 0; i < 16; ++i) {
        const int idx = i * 256 + tid;
        const int n = idx >> 5, q = idx & 31;
        const ushort4 v = ((const ushort4*)Wt)[idx];
        *(ushort4*)&Wl[n * 136 + q * 4] = v;
    }
#pragma unroll
    for (int i = 0; i < 4; ++i) {
        const int idx = i * 256 + tid;
        const int row = idx >> 4, qc = idx & 15;
        const int gr = r0 + row;
        uint4 v = (gr < M) ? ((const uint4*)Ab)[(size_t)gr * 16 + qc]
                           : make_uint4(0, 0, 0, 0);
        const float4 a0 = *(const float4*)&AscL[qc * 8];
        const float4 a1 = *(const float4*)&AscL[qc * 8 + 4];
        const float4 b0 = *(const float4*)&AshL[qc * 8];
        const float4 b1 = *(const float4*)&AshL[qc * 8 + 4];
        float x0 = fmaxf(fmaf(a0.x, blo(v.x), b0.x), 0.f);
        float x1 = fmaxf(fmaf(a0.y, bhi(v.x), b0.y), 0.f);
        float x2 = fmaxf(fmaf(a0.z, blo(v.y), b0.z), 0.f);
        float x3 = fmaxf(fmaf(a0.w, bhi(v.y), b0.w), 0.f);
        float x4 = fmaxf(fmaf(a1.x, blo(v.z), b1.x), 0.f);
        float x5 = fmaxf(fmaf(a1.y, bhi(v.z), b1.y), 0.f);
        float x6 = fmaxf(fmaf(a1.z, blo(v.w), b1.z), 0.f);
        float x7 = fmaxf(fmaf(a1.w, bhi(v.w), b1.w), 0.f);
        uint4 o;
        o.x = (unsigned)f2bf(x0) | ((unsigned)f2bf(x1) << 16);
        o.y = (unsigned)f2bf(x2) | ((unsigned)f2bf(x3) << 16);
        o.z = (unsigned)f2bf(x4) | ((unsigned)f2bf(x5) << 16);
        o.w = (unsigned)f2bf(x6) | ((unsigned)f2bf(x7) << 16);
        *(uint4*)&Al[row * 136 + qc * 8] = o;
    }
    __syncthreads();

    const int wave = tid >> 6, lane = tid & 63;
    const int lrow = lane & 15, quad = lane >> 4;
    const int n0 = wave * 32;

    floatx4 acc[4][2];
#pragma unroll
    for (int mt = 0; mt < 4; ++mt)
#pragma unroll
        for (int t = 0; t < 2; ++t)
#pragma unroll
            for (int j = 0; j < 4; ++j) acc[mt][t][j] = 0.f;

#pragma unroll
    for (int c = 0; c < 4; ++c) {
        const int k0 = c * 32;
        const short8 b0 = *(const short8*)&Wl[(n0 + lrow) * 136 + k0 + quad * 8];
        const short8 b1 = *(const short8*)&Wl[(n0 + 16 + lrow) * 136 + k0 + quad * 8];
#pragma unroll
        for (int mt = 0; mt < 4; ++mt) {
            const short8 a = *(const short8*)&Al[(mt * 16 + lrow) * 136 + k0 + quad * 8];
            acc[mt][0] = __builtin_amdgcn_mfma_f32_16x16x32_bf16(a, b0, acc[mt][0], 0, 0, 0);
            acc[mt][1] = __builtin_amdgcn_mfma_f32_16x16x32_bf16(a, b1, acc[mt][1], 0, 0, 0);
        }
    }
    __syncthreads();

#pragma unroll
    for (int mt = 0; mt < 4; ++mt)
#pragma unroll
        for (int t = 0; t < 2; ++t)
#pragma unroll
            for (int j = 0; j < 4; ++j)
                Cl[(mt * 16 + quad * 4 + j) * 132 + n0 + t * 16 + lrow] = acc[mt][t][j];
    __syncthreads();

#pragma unroll
    for (int i = 0; i < 4; ++i) {
        const int row = i * 16 + (tid >> 4);
        const int c0 = (tid & 15) * 8;
        const int gr = r0 + row;
        if (gr < M) {
            const float4 v0 = *(float4*)&Cl[row * 132 + c0];
            const float4 v1 = *(float4*)&Cl[row * 132 + c0 + 4];
            C[(size_t)gr * 16 + (c0 >> 3)] = pk8_fp8(v0, v1);
        }
    }
}

// ============ atomic-free CSR build: two-level bucket counting sort ============

__global__ __launch_bounds__(256) void bucket_hist(
    const int* __restrict__ src, const int* __restrict__ dst,
    int* __restrict__ cntD, int* __restrict__ cntS, int E, int B, int chunk)
{
    __shared__ int hD[MAXB], hS[MAXB];
    const int tid = threadIdx.x;
    for (int i = tid; i < B; i += 256) { hD[i] = 0; hS[i] = 0; }
    __syncthreads();
    const int lo = blockIdx.x * chunk;
    const int hi = min(E, lo + chunk);
    for (int e = lo + tid; e < hi; e += 256) {
        atomicAdd(&hD[dst[e] >> NPB_SHIFT], 1);
        atomicAdd(&hS[src[e] >> NPB_SHIFT], 1);
    }
    __syncthreads();
    for (int i = tid; i < B; i += 256) {
        cntD[i * PB + blockIdx.x] = hD[i];
        cntS[i * PB + blockIdx.x] = hS[i];
    }
}

__global__ __launch_bounds__(256) void bucket_base(
    const int* __restrict__ cntD, const int* __restrict__ cntS,
    int* __restrict__ baseD, int* __restrict__ baseS, int B, int E)
{
    __shared__ int lD[256], lS[256];
    const int tid = threadIdx.x;
    int sD = 0, sS = 0;
    if (tid < B) {
        const int4* pD = (const int4*)(cntD + tid * PB);
        const int4* pS = (const int4*)(cntS + tid * PB);
        for (int j = 0; j < PB / 4; ++j) {
            const int4 a = pD[j], b = pS[j];
            sD += a.x + a.y + a.z + a.w;
            sS += b.x + b.y + b.z + b.w;
        }
    }
    lD[tid] = sD; lS[tid] = sS;
    __syncthreads();
    for (int st = 1; st < 256; st <<= 1) {
        const int vD = (tid >= st) ? lD[tid - st] : 0;
        const int vS = (tid >= st) ? lS[tid - st] : 0;
        __syncthreads();
        lD[tid] += vD; lS[tid] += vS;
        __syncthreads();
    }
    if (tid < B) { baseD[tid] = lD[tid] - sD; baseS[tid] = lS[tid] - sS; }
    if (tid == 0) { baseD[B] = E; baseS[B] = E; }
}

__global__ __launch_bounds__(256) void bucket_cursor(
    int* __restrict__ cntD, int* __restrict__ cntS,
    const int* __restrict__ baseD, const int* __restrict__ baseS, int B)
{
    int b = blockIdx.x;
    int* cnt; const int* base;
    if (b < B) { cnt = cntD; base = baseD; }
    else       { cnt = cntS; base = baseS; b -= B; }
    __shared__ int ls[256];
    const int tid = threadIdx.x;
    const int c0 = cnt[b * PB + 2 * tid];
    const int c1 = cnt[b * PB + 2 * tid + 1];
    const int s = c0 + c1;
    ls[tid] = s;
    __syncthreads();
    for (int st = 1; st < 256; st <<= 1) {
        const int v = (tid >= st) ? ls[tid - st] : 0;
        __syncthreads();
        ls[tid] += v;
        __syncthreads();
    }
    const int excl = ls[tid] - s + base[b];
    cnt[b * PB + 2 * tid] = excl;
    cnt[b * PB + 2 * tid + 1] = excl + c0;
}

__global__ __launch_bounds__(256) void bucket_place(
    const int* __restrict__ src, const int* __restrict__ dst,
    const float* __restrict__ ew,
    const int* __restrict__ curD, const int* __restrict__ curS,
    uint2* __restrict__ bktD, uint2* __restrict__ bktS, int E, int B, int chunk)
{
    __shared__ int cD[MAXB], cS[MAXB];
    const int tid = threadIdx.x;
    for (int i = tid; i < B; i += 256) {
        cD[i] = curD[i * PB + blockIdx.x];
        cS[i] = curS[i * PB + blockIdx.x];
    }
    __syncthreads();
    const int lo = blockIdx.x * chunk;
    const int hi = min(E, lo + chunk);
    for (int e = lo + tid; e < hi; e += 256) {
        const int s = src[e], d = dst[e];
        const unsigned wb = __float_as_uint(ew[e]);
        const int pd = atomicAdd(&cD[d >> NPB_SHIFT], 1);
        bktD[pd] = make_uint2(((unsigned)s << NPB_SHIFT) | (unsigned)(d & (NPB - 1)), wb);
        const int ps = atomicAdd(&cS[s >> NPB_SHIFT], 1);
        bktS[ps] = make_uint2((unsigned)(s & (NPB - 1)), wb);
    }
}

// merged: blocks [0,B) counting-sort bktD -> rp/packed; blocks [B,2B) cw sums
__global__ __launch_bounds__(256) void bucket_sortcw(
    const uint2* __restrict__ bktD, const int* __restrict__ baseD,
    int* __restrict__ rp, int2* __restrict__ packed,
    const uint2* __restrict__ bktS, const int* __restrict__ baseS,
    float* __restrict__ cw, int N, int B)
{
    const int tid = threadIdx.x;
    if (blockIdx.x >= B) {
        const int b = blockIdx.x - B;
        const int lo = baseS[b], hi = baseS[b + 1];
        __shared__ float sm[NPB];
        sm[2 * tid] = 0.f; sm[2 * tid + 1] = 0.f;
        __syncthreads();
        for (int i = lo + tid; i < hi; i += 256) {
            const uint2 r = bktS[i];
            atomicAdd(&sm[r.x], __uint_as_float(r.y));
        }
        __syncthreads();
        const int n0 = b * NPB + 2 * tid;
        if (n0 < N)     cw[n0]     = sm[2 * tid];
        if (n0 + 1 < N) cw[n0 + 1] = sm[2 * tid + 1];
        return;
    }
    const int b = blockIdx.x;
    const int lo = baseD[b], hi = baseD[b + 1];
    __shared__ int cnt[NPB], cur[NPB];
    __shared__ int ls[256];
    cnt[2 * tid] = 0; cnt[2 * tid + 1] = 0;
    __syncthreads();
    for (int i = lo + tid; i < hi; i += 256)
        atomicAdd(&cnt[bktD[i].x & (NPB - 1)], 1);
    __syncthreads();
    const int c0 = cnt[2 * tid], c1 = cnt[2 * tid + 1];
    const int s = c0 + c1;
    ls[tid] = s;
    __syncthreads();
    for (int st = 1; st < 256; st <<= 1) {
        const int v = (tid >= st) ? ls[tid - st] : 0;
        __syncthreads();
        ls[tid] += v;
        __syncthreads();
    }
    const int excl = ls[tid] - s;
    const int n0 = b * NPB + 2 * tid;
    if (n0 < N)     rp[n0]     = lo + excl + c0;
    if (n0 + 1 < N) rp[n0 + 1] = lo + excl + c0 + c1;
    cur[2 * tid]     = lo + excl;
    cur[2 * tid + 1] = lo + excl + c0;
    __syncthreads();
    for (int i = lo + tid; i < hi; i += 256) {
        const uint2 r = bktD[i];
        const int pos = atomicAdd(&cur[r.x & (NPB - 1)], 1);
        packed[pos] = make_int2((int)(r.x >> NPB_SHIFT), (int)r.y);
    }
}

// ------- fused aggregate + BN stats (v9: fp8 h gathers, half fill traffic) ----
// R8/R11-proven: quarter-wave gathers (lane u holds cols 8u..8u+7), wide
// grid, NSLICE-sliced stats, rp-block + edge prefetch. h is fp8 e4m3: lane
// reads uint2 (8 B) per edge; HW cvt_pk_f32_fp8 unpack (2 vals/op — cheaper
// than bf16 shifts). agg output stays bf16.
#define AGG_R 16
__global__ __launch_bounds__(256) void aggregate4(
    const int2* __restrict__ packed, const int* __restrict__ rp,
    const uint2* __restrict__ h2, uint4* __restrict__ aggb4,
    float* __restrict__ sum, float* __restrict__ sq, int N)
{
    const int tid = threadIdx.x;
    const int lane = tid & 63, wave = tid >> 6;
    const int sub = lane >> 4;          // quarter 0..3 -> edge j+sub
    const int u = lane & 15;            // cols 8u..8u+7
    const int n0 = (blockIdx.x * 4 + wave) * AGG_R;

    // coalesced row-pointer block: lane l holds rp[n0-1+l], l in [0,16]
    int rpv = 0;
    {
        const int idx = n0 - 1 + lane;
        if (lane <= AGG_R && idx >= 0 && idx < N) rpv = rp[idx];
    }

    float csum[8], csq[8];
#pragma unroll
    for (int k = 0; k < 8; ++k) { csum[k] = 0.f; csq[k] = 0.f; }

    // prefetch node 0's first edge chunk
    int2 curE = make_int2(0, 0);
    if (n0 < N) {
        const int s0 = __shfl(rpv, 0, 64), e0 = __shfl(rpv, 1, 64);
        if (lane < min(64, e0 - s0)) curE = packed[s0 + lane];
    }

    for (int r = 0; r < AGG_R; ++r) {
        const int n = n0 + r;
        if (n >= N) break;
        const int start = __shfl(rpv, r, 64);
        const int end   = __shfl(rpv, r + 1, 64);

        // prefetch next node's first chunk (overlaps this node's gathers)
        int2 nextE = make_int2(0, 0);
        if (r + 1 < AGG_R && n + 1 < N) {
            const int ns = __shfl(rpv, r + 1, 64), ne = __shfl(rpv, r + 2, 64);
            if (lane < min(64, ne - ns)) nextE = packed[ns + lane];
        }

        float a[8];
#pragma unroll
        for (int k = 0; k < 8; ++k) a[k] = 0.f;

        for (int base = start; base < end; base += 64) {
            const int cnt = min(64, end - base);
            int2 myE;
            if (base == start) {
                myE = curE;
            } else {
                myE = make_int2(0, 0);
                if (lane < cnt) myE = packed[base + lane];
            }
            for (int j = 0; j < cnt; j += 16) {
                const int i0 = j + sub, i1 = i0 + 4, i2 = i0 + 8, i3 = i0 + 12;
                const int c0 = (i0 < cnt) ? i0 : 0;
                const int c1 = (i1 < cnt) ? i1 : 0;
                const int c2 = (i2 < cnt) ? i2 : 0;
                const int c3 = (i3 < cnt) ? i3 : 0;
                const int s0 = __shfl(myE.x, c0, 64);
                const int s1 = __shfl(myE.x, c1, 64);
                const int s2 = __shfl(myE.x, c2, 64);
                const int s3 = __shfl(myE.x, c3, 64);
                float w0 = __uint_as_float((unsigned)__shfl(myE.y, c0, 64));
                float w1 = __uint_as_float((unsigned)__shfl(myE.y, c1, 64));
                float w2 = __uint_as_float((unsigned)__shfl(myE.y, c2, 64));
                float w3 = __uint_as_float((unsigned)__shfl(myE.y, c3, 64));
                if (i0 >= cnt) w0 = 0.f;
                if (i1 >= cnt) w1 = 0.f;
                if (i2 >= cnt) w2 = 0.f;
                if (i3 >= cnt) w3 = 0.f;
                const uint2 v0 = h2[(size_t)s0 * 16 + u];
                const uint2 v1 = h2[(size_t)s1 * 16 + u];
                const uint2 v2 = h2[(size_t)s2 * 16 + u];
                const uint2 v3 = h2[(size_t)s3 * 16 + u];
                floatx2 f;
#define ACC_EDGE(V, W) \
    f = __builtin_amdgcn_cvt_pk_f32_fp8((int)V.x, false); \
    a[0] = fmaf(W, f.x, a[0]); a[1] = fmaf(W, f.y, a[1]); \
    f = __builtin_amdgcn_cvt_pk_f32_fp8((int)V.x, true);  \
    a[2] = fmaf(W, f.x, a[2]); a[3] = fmaf(W, f.y, a[3]); \
    f = __builtin_amdgcn_cvt_pk_f32_fp8((int)V.y, false); \
    a[4] = fmaf(W, f.x, a[4]); a[5] = fmaf(W, f.y, a[5]); \
    f = __builtin_amdgcn_cvt_pk_f32_fp8((int)V.y, true);  \
    a[6] = fmaf(W, f.x, a[6]); a[7] = fmaf(W, f.y, a[7]);
                ACC_EDGE(v0, w0)
                ACC_EDGE(v1, w1)
                ACC_EDGE(v2, w2)
                ACC_EDGE(v3, w3)
#undef ACC_EDGE
            }
        }
        // reduce across the 4 quarter-waves
#pragma unroll
        for (int k = 0; k < 8; ++k) {
            a[k] += __shfl_xor(a[k], 16, 64);
            a[k] += __shfl_xor(a[k], 32, 64);
        }
        if (sub == 0) {
            uint4 o;
            o.x = (unsigned)f2bf(a[0]) | ((unsigned)f2bf(a[1]) << 16);
            o.y = (unsigned)f2bf(a[2]) | ((unsigned)f2bf(a[3]) << 16);
            o.z = (unsigned)f2bf(a[4]) | ((unsigned)f2bf(a[5]) << 16);
            o.w = (unsigned)f2bf(a[6]) | ((unsigned)f2bf(a[7]) << 16);
            aggb4[(size_t)n * 16 + u] = o;
#pragma unroll
            for (int k = 0; k < 8; ++k) {
                csum[k] += a[k];
                csq[k] = fmaf(a[k], a[k], csq[k]);
            }
        }
        curE = nextE;
    }

    __shared__ float lsum[512], lsq[512];   // [wave][col=u*8+k]
    if (sub == 0) {
#pragma unroll
        for (int k = 0; k < 8; ++k) {
            lsum[wave * 128 + u * 8 + k] = csum[k];
            lsq[wave * 128 + u * 8 + k] = csq[k];
        }
    }
    __syncthreads();
    if (tid < 128) {
        const float s = lsum[tid] + lsum[128 + tid] + lsum[256 + tid] + lsum[384 + tid];
        const float q = lsq[tid] + lsq[128 + tid] + lsq[256 + tid] + lsq[384 + tid];
        const int sl = (blockIdx.x & (NSLICE - 1)) * 128;
        atomicAdd(&sum[sl + tid], s);
        atomicAdd(&sq[sl + tid], q);
    }
}

// ---------------- collapsed layer 2 (persistent grid, sliced-stat prologue) ----
__global__ __launch_bounds__(256) void wcolsum_bf16(
    const unsigned* __restrict__ xb, const float* __restrict__ cw,
    const float* __restrict__ sum1, const float* __restrict__ sq1,
    const float* __restrict__ g, const float* __restrict__ be,
    float* __restrict__ sout, int N)
{
    __shared__ float Aaf[128], Baf[128];
    __shared__ float2 ls[256];
    const int tid = threadIdx.x;
    if (tid < 128) {
        float s = 0.f, q = 0.f;
#pragma unroll
        for (int k = 0; k < NSLICE; ++k) {
            s += sum1[k * 128 + tid];
            q += sq1[k * 128 + tid];
        }
        const float invN = 1.0f / (float)N;
        const float m = s * invN;
        const float var = q * invN - m * m;
        const float rs = rsqrtf(var + BN_EPS);
        Aaf[tid] = g[tid] * rs;
        Baf[tid] = be[tid] - g[tid] * m * rs;
    }
    __syncthreads();
    const int u = tid & 63, rr = tid >> 6;
    const float ax = Aaf[2 * u], ay = Aaf[2 * u + 1];
    const float bx = Baf[2 * u], by = Baf[2 * u + 1];
    float2 s = {0.f, 0.f};
    for (int row = blockIdx.x * 4 + rr; row < N; row += gridDim.x * 4) {
        const unsigned v = xb[(size_t)row * 64 + u];
        const float c = cw[row];
        const float x = fmaxf(fmaf(ax, blo(v), bx), 0.f);
        const float y = fmaxf(fmaf(ay, bhi(v), by), 0.f);
        s.x = fmaf(c, x, s.x);
        s.y = fmaf(c, y, s.y);
    }
    ls[tid] = s;
    __syncthreads();
    if (tid < 64) {
        float sx = ls[tid].x + ls[64 + tid].x + ls[128 + tid].x + ls[192 + tid].x;
        float sy = ls[tid].y + ls[64 + tid].y + ls[128 + tid].y + ls[192 + tid].y;
        atomicAdd(&sout[2 * tid + 0], sx);
        atomicAdd(&sout[2 * tid + 1], sy);
    }
}

__global__ void final_out(
    const float* __restrict__ s, const float* __restrict__ W2,
    const float* __restrict__ b2, float* __restrict__ out, int N, int Dout)
{
    const int j = threadIdx.x;
    if (j < Dout) {
        float acc = 0.f;
        for (int f = 0; f < 128; ++f) acc = fmaf(s[f], W2[f * Dout + j], acc);
        out[j] = acc + (float)N * b2[j];
    }
}

extern "C" void kernel_launch(void* const* d_in, const int* in_sizes, int n_in,
                              void* d_out, int out_size, void* d_ws, size_t ws_size,
                              hipStream_t stream)
{
    const float* nf  = (const float*)d_in[0];
    const int*   ei  = (const int*)d_in[1];
    const float* ew  = (const float*)d_in[2];
    const float* W0  = (const float*)d_in[3];
    // b0 = d_in[4], b1 = d_in[6]: cancel inside BatchNorm, unused
    const float* W1  = (const float*)d_in[5];
    const float* W2  = (const float*)d_in[7];
    const float* b2  = (const float*)d_in[8];
    const float* g0  = (const float*)d_in[9];
    const float* be0 = (const float*)d_in[10];
    const float* g1  = (const float*)d_in[11];
    const float* be1 = (const float*)d_in[12];

    const int N = in_sizes[0] / 128;
    const int E = in_sizes[2];
    const int* srcI = ei;       // edge_index[0,:]
    const int* dstI = ei + E;   // edge_index[1,:]

    const int B = (N + NPB - 1) / NPB;        // 196 for N=100k
    const int chunk = (E + PB - 1) / PB;

    const size_t HB = ((size_t)N * 128 * 2 + 255) & ~(size_t)255;  // bf16 buf
    const size_t NA = ((size_t)N * sizeof(int) + 255) & ~(size_t)255;
    const size_t CB = (((size_t)B * PB * 4) + 255) & ~(size_t)255;
    char* ws = (char*)d_ws;
    size_t off = 0;
    float* cw    = (float*)(ws + off); off += NA;
    int*   rp    = (int*)  (ws + off); off += NA;
    float* stats = (float*)(ws + off); off += 36864;   // 4 sliced arrays + svec
    int*   cntD  = (int*)  (ws + off); off += CB;
    int*   cntS  = (int*)  (ws + off); off += CB;
    int*   baseD = (int*)  (ws + off); off += 2048;
    int*   baseS = (int*)  (ws + off); off += 2048;
    uint2* hbuf  = (uint2*)(ws + off); off += HB;      // h (fp8, oversized ok)
    unsigned* aggb = (unsigned*)(ws + off); off += HB; // agg (bf16)
    int2*  packed = (int2*)(ws + off); off += (size_t)E * 8;
    uint2* bktD  = (uint2*)(ws + off); off += (size_t)E * 8;
    uint2* bktS  = (uint2*)(ws + off); off += (size_t)E * 8;
    unsigned short* wt0 = (unsigned short*)(ws + off); off += 32768;
    unsigned short* wt1 = (unsigned short*)(ws + off); off += 32768;
    (void)ws_size;  // rounds 1-11 proved ws_size >= 116.5 MB; this needs ~92 MB

    // sliced stats: each array NSLICE*128 floats
    float* sum0 = stats + 0 * NSLICE * 128;
    float* sq0  = stats + 1 * NSLICE * 128;
    float* sum1 = stats + 2 * NSLICE * 128;
    float* sq1  = stats + 3 * NSLICE * 128;
    float* svec = stats + 4 * NSLICE * 128;   // [128]

    const int gemmGrid = (N + 63) / 64;
    const int aggGrid  = (N + 4 * AGG_R - 1) / (4 * AGG_R);   // 1563

    // ---- atomic-free CSR build + cw (graph identical both layers) ----
    bucket_hist<<<PB, 256, 0, stream>>>(srcI, dstI, cntD, cntS, E, B, chunk);
    bucket_base<<<1, 256, 0, stream>>>(cntD, cntS, baseD, baseS, B, E);
    bucket_cursor<<<2 * B, 256, 0, stream>>>(cntD, cntS, baseD, baseS, B);
    bucket_place<<<PB, 256, 0, stream>>>(srcI, dstI, ew, cntD, cntS, bktD, bktS, E, B, chunk);
    bucket_sortcw<<<2 * B, 256, 0, stream>>>(bktD, baseD, rp, packed,
                                             bktS, baseS, cw, N, B);
    wconv<<<64, 256, 0, stream>>>(W0, W1, wt0, wt1, stats);   // + stats zeroing

    // ---- layer 0 ----
    gemm0<<<gemmGrid, 256, 0, stream>>>(nf, wt0, hbuf, N);
    aggregate4<<<aggGrid, 256, 0, stream>>>(
        packed, rp, (const uint2*)hbuf, (uint4*)aggb, sum0, sq0, N);

    // ---- layer 1 (BN0+ReLU folded into GEMM staging) ----
    gemm1<<<gemmGrid, 256, 0, stream>>>(aggb, wt1, hbuf, sum0, sq0, g0, be0, N, N);
    aggregate4<<<aggGrid, 256, 0, stream>>>(
        packed, rp, (const uint2*)hbuf, (uint4*)aggb, sum1, sq1, N);

    // ---- collapsed layer 2: out = (sum_n cw[n]*relu(BN1(x2))[n,:]) @ W2 + N*b2 ----
    wcolsum_bf16<<<256, 256, 0, stream>>>(aggb, cw, sum1, sq1, g1, be1, svec, N);
    final_out<<<1, 64, 0, stream>>>(svec, W2, b2, (float*)d_out, N, out_size);
}